// Round 2
// baseline (1635.178 us; speedup 1.0000x reference)
//
#include <hip/hip_runtime.h>
#include <hip/hip_bf16.h>

#define N_ROWS 4096
#define H_DIM  512
#define V_DIM  50257
#define BM 128
#define BN 128
#define BK 32
#define VT_TOTAL 393            // ceil(V/BN)
#define V_PAD (VT_TOTAL * BN)   // 50304
#define NCHUNK 131              // 393 = 3*131 -> every block exactly 3 tiles
#define LOG2E 1.4426950408889634f

typedef __attribute__((ext_vector_type(8))) short short8;
typedef __attribute__((ext_vector_type(4))) float f32x4;

static __device__ __forceinline__ unsigned short f2bf(float f) {
  unsigned u = __float_as_uint(f);
  u = (u + 0x7fffu + ((u >> 16) & 1u)) >> 16;   // RNE
  return (unsigned short)u;
}

static __device__ __forceinline__ void gload_lds16(const void* g, void* l) {
  __builtin_amdgcn_global_load_lds(
      (const __attribute__((address_space(1))) void*)g,
      (__attribute__((address_space(3))) void*)l, 16, 0, 0);
}

// ---------------- kernel A: fp32 -> bf16 conversion (W padded to V_PAD) ----
__global__ void convert_kernel(const float* __restrict__ X,
                               const float* __restrict__ W,
                               __hip_bfloat16* __restrict__ Xb,
                               __hip_bfloat16* __restrict__ Wb) {
  const long wtot8 = (long)V_PAD * H_DIM / 8;   // 3,219,456
  const long xtot8 = (long)N_ROWS * H_DIM / 8;  //   262,144
  long i = (long)blockIdx.x * blockDim.x + threadIdx.x;
  unsigned short o[8];
  if (i < wtot8) {
    long base = i * 8;
    long row = base >> 9;   // /512
    if (row < V_DIM) {
      const float4* s = (const float4*)(W + base);
      float4 a = s[0], b = s[1];
      o[0]=f2bf(a.x); o[1]=f2bf(a.y); o[2]=f2bf(a.z); o[3]=f2bf(a.w);
      o[4]=f2bf(b.x); o[5]=f2bf(b.y); o[6]=f2bf(b.z); o[7]=f2bf(b.w);
    } else {
      #pragma unroll
      for (int k = 0; k < 8; ++k) o[k] = 0;
    }
    *(short8*)(Wb + base) = *(const short8*)o;
  } else if (i < wtot8 + xtot8) {
    long base = (i - wtot8) * 8;
    const float4* s = (const float4*)(X + base);
    float4 a = s[0], b = s[1];
    o[0]=f2bf(a.x); o[1]=f2bf(a.y); o[2]=f2bf(a.z); o[3]=f2bf(a.w);
    o[4]=f2bf(b.x); o[5]=f2bf(b.y); o[6]=f2bf(b.z); o[7]=f2bf(b.w);
    *(short8*)(Xb + base) = *(const short8*)o;
  }
}

// prefetch one 128x128 fp32 targets tile into LDS via global_load_lds.
// LDS layout: linear [128 rows][128 cols] f32 (64 KB). 16 sites/thread;
// site i + wave w covers LDS bytes [i*4096 + w*1024, +1024).
static __device__ __forceinline__ void prefetch_T(const float* __restrict__ targets,
                                                  char* TsB, int brow, int vt,
                                                  int wid, int lane) {
  const long vb = (long)vt * BN;
  const long lim = (long)N_ROWS * V_DIM - 4;
  #pragma unroll
  for (int i = 0; i < 16; ++i) {
    const int boff = i * 4096 + wid * 1024 + lane * 16;  // byte offset in Ts
    const int trow = boff >> 9;                          // /512 B per row
    const int tcol = (boff & 511) >> 2;                  // float col
    long off = (long)(brow * BM + trow) * V_DIM + vb + tcol;
    off = off > lim ? lim : off;                         // clamp (guard tile OOB)
    gload_lds16(targets + off, TsB + i * 4096 + wid * 1024);
  }
}

// epilogue: bias add + targets (from LDS) + online stats, defer-max thr=12
template <bool GUARD>
static __device__ __forceinline__ void epilogue(const float* __restrict__ Ts,
                                                const float* __restrict__ bias,
                                                int wm, int wn, int q, int c15,
                                                int vbase, f32x4 (&acc)[4][4],
                                                float* ml, float* sl,
                                                float* mt, float* st, float* dd) {
  const int cb = vbase + wn * 64;
  float bv[4];
  bool valn[4];
  #pragma unroll
  for (int n = 0; n < 4; ++n) {
    int col = cb + n * 16 + c15;
    valn[n] = !GUARD || (col < V_DIM);
    bv[n] = valn[n] ? bias[col] : 0.f;
  }
  #pragma unroll
  for (int m = 0; m < 4; ++m) {
    const int rloc0 = wm * 64 + m * 16 + q * 4;
    #pragma unroll
    for (int j = 0; j < 4; ++j) {
      const int i = m * 4 + j;
      const int rbase = (rloc0 + j) << 7;   // *128 floats per Ts row
      float L[4], T[4];
      #pragma unroll
      for (int n = 0; n < 4; ++n) {
        float lv = acc[m][n][j] + bv[n];
        float tv = Ts[rbase + wn * 64 + n * 16 + c15];
        L[n] = (!GUARD || valn[n]) ? lv : -1e30f;
        T[n] = (!GUARD || valn[n]) ? tv : -1e30f;
      }
      // --- logits lse (online, defer-max) ---
      float g = fmaxf(fmaxf(L[0], L[1]), fmaxf(L[2], L[3]));
      if (g > ml[i] + 12.f) {
        sl[i] *= exp2f((ml[i] - g) * LOG2E);
        ml[i] = g;
      }
      float bl = ml[i] * LOG2E;
      float x0 = exp2f(__builtin_fmaf(L[0], LOG2E, -bl));
      float x1 = exp2f(__builtin_fmaf(L[1], LOG2E, -bl));
      float x2 = exp2f(__builtin_fmaf(L[2], LOG2E, -bl));
      float x3 = exp2f(__builtin_fmaf(L[3], LOG2E, -bl));
      sl[i] += (x0 + x1) + (x2 + x3);
      // --- targets softmax num/denom (online, defer-max) ---
      float gt = fmaxf(fmaxf(T[0], T[1]), fmaxf(T[2], T[3]));
      if (gt > mt[i] + 12.f) {
        float sc = exp2f((mt[i] - gt) * LOG2E);
        st[i] *= sc; dd[i] *= sc; mt[i] = gt;
      }
      float bt = mt[i] * LOG2E;
      float e0 = exp2f(__builtin_fmaf(T[0], LOG2E, -bt));
      float e1 = exp2f(__builtin_fmaf(T[1], LOG2E, -bt));
      float e2 = exp2f(__builtin_fmaf(T[2], LOG2E, -bt));
      float e3 = exp2f(__builtin_fmaf(T[3], LOG2E, -bt));
      st[i] += (e0 + e1) + (e2 + e3);
      dd[i] += (e0 * L[0] + e1 * L[1]) + (e2 * L[2] + e3 * L[3]);
    }
  }
}

// ---------------- kernel B: fused GEMM + online softmax stats -------------
// Grid (32, NCHUNK). Block 256 = 4 waves (2x2 over the 128x128 tile).
__global__ __launch_bounds__(256, 2)
void fused_kernel(const __hip_bfloat16* __restrict__ Xb,
                  const __hip_bfloat16* __restrict__ Wb,
                  const float* __restrict__ bias,
                  const float* __restrict__ targets,
                  float* __restrict__ partials) {
  __shared__ __align__(16) char smem[81920];
  __hip_bfloat16* As = (__hip_bfloat16*)smem;          //  8 KB [128][32]
  __hip_bfloat16* Bs = (__hip_bfloat16*)(smem + 8192); //  8 KB [128][32]
  float* Ts = (float*)(smem + 16384);                  // 64 KB [128][128]
  char* AsB = smem;
  char* BsB = smem + 8192;
  char* TsB = smem + 16384;

  const int tid  = threadIdx.x;
  const int lane = tid & 63;
  const int wid  = tid >> 6;
  const int wm   = wid >> 1;
  const int wn   = wid & 1;
  const int q    = lane >> 4;
  const int c15  = lane & 15;
  const int brow = blockIdx.x;
  const int chunk = blockIdx.y;

  float ml[16], sl[16], mt[16], st[16], dd[16];
  #pragma unroll
  for (int i = 0; i < 16; ++i) {
    ml[i] = -1e30f; sl[i] = 0.f; mt[i] = -1e30f; st[i] = 0.f; dd[i] = 0.f;
  }

  const int srow = tid >> 2;
  const int sk   = (tid & 3) * 8;
  const long abase = (long)(brow * BM + srow) * H_DIM + sk;

  prefetch_T(targets, TsB, brow, chunk, wid, lane);

  #pragma unroll 1
  for (int vt = chunk; vt < VT_TOTAL; vt += NCHUNK) {
    const int vbase = vt * BN;

    f32x4 acc[4][4];
    #pragma unroll
    for (int m = 0; m < 4; ++m)
      #pragma unroll
      for (int n = 0; n < 4; ++n)
        acc[m][n] = (f32x4){0.f, 0.f, 0.f, 0.f};

    const long bbase = (long)(vbase + srow) * H_DIM + sk;

    for (int kk = 0; kk < H_DIM; kk += BK) {
      gload_lds16(Xb + abase + kk,              AsB + wid * 1024);
      gload_lds16(Xb + abase + 64 * H_DIM + kk, AsB + 4096 + wid * 1024);
      gload_lds16(Wb + bbase + kk,              BsB + wid * 1024);
      gload_lds16(Wb + bbase + 64 * H_DIM + kk, BsB + 4096 + wid * 1024);
      __syncthreads();
      short8 af[4], bfr[4];
      #pragma unroll
      for (int m = 0; m < 4; ++m)
        af[m] = *(const short8*)&As[(wm * 64 + m * 16 + c15) * BK + q * 8];
      #pragma unroll
      for (int n = 0; n < 4; ++n)
        bfr[n] = *(const short8*)&Bs[(wn * 64 + n * 16 + c15) * BK + q * 8];
      #pragma unroll
      for (int m = 0; m < 4; ++m)
        #pragma unroll
        for (int n = 0; n < 4; ++n)
          acc[m][n] = __builtin_amdgcn_mfma_f32_16x16x32_bf16(af[m], bfr[n], acc[m][n], 0, 0, 0);
      __syncthreads();
    }

    if (vt == VT_TOTAL - 1)
      epilogue<true>(Ts, bias, wm, wn, q, c15, vbase, acc, ml, sl, mt, st, dd);
    else
      epilogue<false>(Ts, bias, wm, wn, q, c15, vbase, acc, ml, sl, mt, st, dd);

    __syncthreads();   // all Ts reads done before next prefetch overwrites
    if (vt + NCHUNK < VT_TOTAL)
      prefetch_T(targets, TsB, brow, vt + NCHUNK, wid, lane);
  }

  // butterfly-merge the 16 lanes (c15 bits) of each q-group
  #pragma unroll
  for (int off = 1; off <= 8; off <<= 1) {
    #pragma unroll
    for (int i = 0; i < 16; ++i) {
      float ml2 = __shfl_xor(ml[i], off);
      float sl2 = __shfl_xor(sl[i], off);
      float mt2 = __shfl_xor(mt[i], off);
      float st2 = __shfl_xor(st[i], off);
      float dd2 = __shfl_xor(dd[i], off);
      float nm = fmaxf(ml[i], ml2);
      sl[i] = sl[i] * exp2f((ml[i] - nm) * LOG2E) + sl2 * exp2f((ml2 - nm) * LOG2E);
      ml[i] = nm;
      float nmt = fmaxf(mt[i], mt2);
      float e1 = exp2f((mt[i] - nmt) * LOG2E);
      float e2 = exp2f((mt2 - nmt) * LOG2E);
      st[i] = st[i] * e1 + st2 * e2;
      dd[i] = dd[i] * e1 + dd2 * e2;
      mt[i] = nmt;
    }
  }

  // cross-wn merge via LDS (reuse As region), one partial per (row, chunk)
  __syncthreads();
  float* M = (float*)smem;   // 128 rows x 5 floats = 2560 B
  if (wn == 1 && c15 == 0) {
    #pragma unroll
    for (int m = 0; m < 4; ++m)
      #pragma unroll
      for (int j = 0; j < 4; ++j) {
        int i = m * 4 + j;
        int r = wm * 64 + m * 16 + q * 4 + j;
        float* p = M + r * 5;
        p[0] = ml[i]; p[1] = sl[i]; p[2] = mt[i]; p[3] = st[i]; p[4] = dd[i];
      }
  }
  __syncthreads();
  if (wn == 0 && c15 == 0) {
    #pragma unroll
    for (int m = 0; m < 4; ++m)
      #pragma unroll
      for (int j = 0; j < 4; ++j) {
        int i = m * 4 + j;
        int r = wm * 64 + m * 16 + q * 4 + j;
        const float* p = M + r * 5;
        float ml2 = p[0], sl2 = p[1], mt2 = p[2], st2 = p[3], dd2 = p[4];
        float nm = fmaxf(ml[i], ml2);
        float slo = sl[i] * exp2f((ml[i] - nm) * LOG2E) + sl2 * exp2f((ml2 - nm) * LOG2E);
        float nmt = fmaxf(mt[i], mt2);
        float e1 = exp2f((mt[i] - nmt) * LOG2E);
        float e2 = exp2f((mt2 - nmt) * LOG2E);
        float sto = st[i] * e1 + st2 * e2;
        float ddo = dd[i] * e1 + dd2 * e2;
        long rg = (long)(brow * BM + r);
        float* o = partials + (rg * NCHUNK + chunk) * 5;
        o[0] = nm; o[1] = slo; o[2] = nmt; o[3] = sto; o[4] = ddo;
      }
  }
}

// ---------------- kernel C: merge partials -> per-row loss ----------------
__global__ void rowloss_kernel(const float* __restrict__ partials,
                               float* __restrict__ rowloss) {
  int r = blockIdx.x * blockDim.x + threadIdx.x;
  if (r >= N_ROWS) return;
  const float* p = partials + (long)r * NCHUNK * 5;
  float ml = -1e30f, sl = 0.f, mt = -1e30f, st = 0.f, dd = 0.f;
  for (int c = 0; c < NCHUNK; ++c) {
    float ml2 = p[0], sl2 = p[1], mt2 = p[2], st2 = p[3], dd2 = p[4];
    p += 5;
    float nm = fmaxf(ml, ml2);
    sl = sl * exp2f((ml - nm) * LOG2E) + sl2 * exp2f((ml2 - nm) * LOG2E);
    ml = nm;
    float nmt = fmaxf(mt, mt2);
    float e1 = exp2f((mt - nmt) * LOG2E);
    float e2 = exp2f((mt2 - nmt) * LOG2E);
    st = st * e1 + st2 * e2;
    dd = dd * e1 + dd2 * e2;
    mt = nmt;
  }
  float lse = ml + logf(sl);
  rowloss[r] = lse - dd / st;
}

// ---------------- kernel D: final scalar reduce ---------------------------
__global__ void final_kernel(const float* __restrict__ rowloss,
                             float* __restrict__ out) {
  __shared__ float sm[4];
  float s = 0.f;
  for (int i = threadIdx.x; i < N_ROWS; i += 256) s += rowloss[i];
  #pragma unroll
  for (int off = 32; off > 0; off >>= 1) s += __shfl_down(s, off);
  if ((threadIdx.x & 63) == 0) sm[threadIdx.x >> 6] = s;
  __syncthreads();
  if (threadIdx.x == 0) out[0] = (sm[0] + sm[1] + sm[2] + sm[3]) * (1.0f / (float)N_ROWS);
}

extern "C" void kernel_launch(void* const* d_in, const int* in_sizes, int n_in,
                              void* d_out, int out_size, void* d_ws, size_t ws_size,
                              hipStream_t stream) {
  const float* x       = (const float*)d_in[0];   // [4096, 512]
  const float* targets = (const float*)d_in[1];   // [4096, 50257]
  const float* weight  = (const float*)d_in[2];   // [50257, 512]
  const float* bias    = (const float*)d_in[3];   // [50257]
  float* out = (float*)d_out;

  char* ws = (char*)d_ws;
  __hip_bfloat16* Wb = (__hip_bfloat16*)ws;                     // 51,511,296 B
  size_t off = (size_t)V_PAD * H_DIM * 2;
  __hip_bfloat16* Xb = (__hip_bfloat16*)(ws + off);             //  4,194,304 B
  off += (size_t)N_ROWS * H_DIM * 2;
  float* partials = (float*)(ws + off);                         // 10,731,520 B
  off += (size_t)N_ROWS * NCHUNK * 5 * sizeof(float);
  float* rowloss = (float*)(ws + off);                          //     16,384 B

  convert_kernel<<<13600, 256, 0, stream>>>(x, weight, Xb, Wb);
  dim3 grid(N_ROWS / BM, NCHUNK);
  fused_kernel<<<grid, 256, 0, stream>>>(Xb, Wb, bias, targets, partials);
  rowloss_kernel<<<N_ROWS / 256, 256, 0, stream>>>(partials, rowloss);
  final_kernel<<<1, 256, 0, stream>>>(rowloss, out);
}

// Round 3
// 943.614 us; speedup vs baseline: 1.7329x; 1.7329x over previous
//
#include <hip/hip_runtime.h>
#include <hip/hip_bf16.h>

#define N_ROWS 4096
#define H_DIM  512
#define V_DIM  50257
#define BM 128
#define BN 128
#define BK 32
#define VT_TOTAL 393            // ceil(V/BN)
#define V_PAD (VT_TOTAL * BN)   // 50304
#define NCHUNK 131              // 393 = 3*131 -> every block exactly 3 tiles
#define LOG2E 1.4426950408889634f

typedef __attribute__((ext_vector_type(8))) short short8;
typedef __attribute__((ext_vector_type(4))) float f32x4;

static __device__ __forceinline__ unsigned short f2bf(float f) {
  unsigned u = __float_as_uint(f);
  u = (u + 0x7fffu + ((u >> 16) & 1u)) >> 16;   // RNE
  return (unsigned short)u;
}

static __device__ __forceinline__ void gload_lds16(const void* g, void* l) {
  __builtin_amdgcn_global_load_lds(
      (const __attribute__((address_space(1))) void*)g,
      (__attribute__((address_space(3))) void*)l, 16, 0, 0);
}

// ---------------- kernel A: fp32 -> bf16 conversion (W padded to V_PAD) ----
__global__ void convert_kernel(const float* __restrict__ X,
                               const float* __restrict__ W,
                               __hip_bfloat16* __restrict__ Xb,
                               __hip_bfloat16* __restrict__ Wb) {
  const long wtot8 = (long)V_PAD * H_DIM / 8;   // 3,219,456
  const long xtot8 = (long)N_ROWS * H_DIM / 8;  //   262,144
  long i = (long)blockIdx.x * blockDim.x + threadIdx.x;
  unsigned short o[8];
  if (i < wtot8) {
    long base = i * 8;
    long row = base >> 9;   // /512
    if (row < V_DIM) {
      const float4* s = (const float4*)(W + base);
      float4 a = s[0], b = s[1];
      o[0]=f2bf(a.x); o[1]=f2bf(a.y); o[2]=f2bf(a.z); o[3]=f2bf(a.w);
      o[4]=f2bf(b.x); o[5]=f2bf(b.y); o[6]=f2bf(b.z); o[7]=f2bf(b.w);
    } else {
      #pragma unroll
      for (int k = 0; k < 8; ++k) o[k] = 0;
    }
    *(short8*)(Wb + base) = *(const short8*)o;
  } else if (i < wtot8 + xtot8) {
    long base = (i - wtot8) * 8;
    const float4* s = (const float4*)(X + base);
    float4 a = s[0], b = s[1];
    o[0]=f2bf(a.x); o[1]=f2bf(a.y); o[2]=f2bf(a.z); o[3]=f2bf(a.w);
    o[4]=f2bf(b.x); o[5]=f2bf(b.y); o[6]=f2bf(b.z); o[7]=f2bf(b.w);
    *(short8*)(Xb + base) = *(const short8*)o;
  }
}

// epilogue: swapped-layout stats update. Each thread owns 4 x-rows
// (a, c15) x 16 vocab entries (wn, b, q, j). Targets loads: 1 base addr
// per row + imm-offset scalar loads, processed in 8-wide halves.
template <bool GUARD>
static __device__ __forceinline__ void epilogue(
    const float* __restrict__ targets, const float* __restrict__ bias,
    int brow, int vbase, int wm, int wn, int q, int c15,
    const f32x4 (&acc)[4][4],
    float ml[4], float sl[4], float mt[4], float st[4], float dd[4]) {
  const int v0 = vbase + wn * 64 + q * 4;   // thread's vocab base (+b*16+j)

  // bias for the 16 vocab entries (shared across the 4 rows)
  float bv[16];
  if (GUARD) {
    #pragma unroll
    for (int b = 0; b < 4; ++b)
      #pragma unroll
      for (int j = 0; j < 4; ++j) {
        int col = v0 + b * 16 + j;
        bv[b * 4 + j] = (col < V_DIM) ? bias[col] : 0.f;
      }
  } else {
    #pragma unroll
    for (int b = 0; b < 4; ++b) {
      float4 t = *(const float4*)&bias[v0 + b * 16];
      bv[b * 4 + 0] = t.x; bv[b * 4 + 1] = t.y;
      bv[b * 4 + 2] = t.z; bv[b * 4 + 3] = t.w;
    }
  }

  #pragma unroll
  for (int a = 0; a < 4; ++a) {
    const long row = (long)(brow * BM + wm * 64 + a * 16 + c15);
    const float* tb = targets + row * V_DIM + v0;
    #pragma unroll
    for (int h = 0; h < 2; ++h) {          // halves: b = {2h, 2h+1}
      float T[8], L[8];
      #pragma unroll
      for (int bb = 0; bb < 2; ++bb) {
        const int b = 2 * h + bb;
        #pragma unroll
        for (int j = 0; j < 4; ++j) {
          const int k = bb * 4 + j;
          if (GUARD) {
            const int col = v0 + b * 16 + j;
            const bool ok = (col < V_DIM);
            T[k] = ok ? tb[b * 16 + j] : -1e30f;
            L[k] = ok ? (acc[a][b][j] + bv[b * 4 + j]) : -1e30f;
          } else {
            T[k] = tb[b * 16 + j];
            L[k] = acc[a][b][j] + bv[b * 4 + j];
          }
        }
      }
      // logits lse (online, defer-max thr=12)
      float g = fmaxf(fmaxf(fmaxf(L[0], L[1]), fmaxf(L[2], L[3])),
                      fmaxf(fmaxf(L[4], L[5]), fmaxf(L[6], L[7])));
      if (g > ml[a] + 12.f) {
        sl[a] *= exp2f((ml[a] - g) * LOG2E);
        ml[a] = g;
      }
      float bl = ml[a] * LOG2E;
      float ss = 0.f;
      #pragma unroll
      for (int k = 0; k < 8; ++k)
        ss += exp2f(__builtin_fmaf(L[k], LOG2E, -bl));
      sl[a] += ss;
      // targets softmax num/denom (online, defer-max thr=12)
      float gt = fmaxf(fmaxf(fmaxf(T[0], T[1]), fmaxf(T[2], T[3])),
                       fmaxf(fmaxf(T[4], T[5]), fmaxf(T[6], T[7])));
      if (gt > mt[a] + 12.f) {
        float sc = exp2f((mt[a] - gt) * LOG2E);
        st[a] *= sc; dd[a] *= sc; mt[a] = gt;
      }
      float bt = mt[a] * LOG2E;
      float s2 = 0.f, d2 = 0.f;
      #pragma unroll
      for (int k = 0; k < 8; ++k) {
        float e = exp2f(__builtin_fmaf(T[k], LOG2E, -bt));
        s2 += e;
        d2 = __builtin_fmaf(e, L[k], d2);
      }
      st[a] += s2; dd[a] += d2;
    }
  }
}

// ---------------- kernel B: fused GEMM + online softmax stats -------------
// Grid (32, NCHUNK). Block 256 = 4 waves (2x2 over the 128x128 tile).
// Swapped MFMA: acc[a][b] = mfma(W_frag[b], X_frag[a]) so output cols = x-rows.
__global__ __launch_bounds__(256, 3)
void fused_kernel(const __hip_bfloat16* __restrict__ Xb,
                  const __hip_bfloat16* __restrict__ Wb,
                  const float* __restrict__ bias,
                  const float* __restrict__ targets,
                  float* __restrict__ partials) {
  __shared__ __align__(16) char smem[16384];
  __hip_bfloat16* As = (__hip_bfloat16*)smem;          // 8 KB [128][32]
  __hip_bfloat16* Bs = (__hip_bfloat16*)(smem + 8192); // 8 KB [128][32]
  char* AsB = smem;
  char* BsB = smem + 8192;

  const int tid  = threadIdx.x;
  const int lane = tid & 63;
  const int wid  = tid >> 6;
  const int wm   = wid >> 1;
  const int wn   = wid & 1;
  const int q    = lane >> 4;
  const int c15  = lane & 15;
  const int brow = blockIdx.x;
  const int chunk = blockIdx.y;

  float ml[4], sl[4], mt[4], st[4], dd[4];
  #pragma unroll
  for (int a = 0; a < 4; ++a) {
    ml[a] = -1e30f; sl[a] = 0.f; mt[a] = -1e30f; st[a] = 0.f; dd[a] = 0.f;
  }

  const int srow = tid >> 2;
  const int sk   = (tid & 3) * 8;
  const long abase = (long)(brow * BM + srow) * H_DIM + sk;

  #pragma unroll 1
  for (int vt = chunk; vt < VT_TOTAL; vt += NCHUNK) {
    const int vbase = vt * BN;

    f32x4 acc[4][4];
    #pragma unroll
    for (int a = 0; a < 4; ++a)
      #pragma unroll
      for (int b = 0; b < 4; ++b)
        acc[a][b] = (f32x4){0.f, 0.f, 0.f, 0.f};

    const long bbase = (long)(vbase + srow) * H_DIM + sk;

    for (int kk = 0; kk < H_DIM; kk += BK) {
      gload_lds16(Xb + abase + kk,              AsB + wid * 1024);
      gload_lds16(Xb + abase + 64 * H_DIM + kk, AsB + 4096 + wid * 1024);
      gload_lds16(Wb + bbase + kk,              BsB + wid * 1024);
      gload_lds16(Wb + bbase + 64 * H_DIM + kk, BsB + 4096 + wid * 1024);
      __syncthreads();
      short8 xf[4], wf[4];
      #pragma unroll
      for (int a = 0; a < 4; ++a)
        xf[a] = *(const short8*)&As[(wm * 64 + a * 16 + c15) * BK + q * 8];
      #pragma unroll
      for (int b = 0; b < 4; ++b)
        wf[b] = *(const short8*)&Bs[(wn * 64 + b * 16 + c15) * BK + q * 8];
      #pragma unroll
      for (int a = 0; a < 4; ++a)
        #pragma unroll
        for (int b = 0; b < 4; ++b)
          acc[a][b] = __builtin_amdgcn_mfma_f32_16x16x32_bf16(wf[b], xf[a], acc[a][b], 0, 0, 0);
      __syncthreads();
    }

    if (vt == VT_TOTAL - 1)
      epilogue<true>(targets, bias, brow, vbase, wm, wn, q, c15, acc, ml, sl, mt, st, dd);
    else
      epilogue<false>(targets, bias, brow, vbase, wm, wn, q, c15, acc, ml, sl, mt, st, dd);
  }

  // merge the 4 q-lanes (lane bits 4,5) holding disjoint vocab slices
  #pragma unroll
  for (int off = 16; off <= 32; off <<= 1) {
    #pragma unroll
    for (int a = 0; a < 4; ++a) {
      float ml2 = __shfl_xor(ml[a], off);
      float sl2 = __shfl_xor(sl[a], off);
      float mt2 = __shfl_xor(mt[a], off);
      float st2 = __shfl_xor(st[a], off);
      float dd2 = __shfl_xor(dd[a], off);
      float nm = fmaxf(ml[a], ml2);
      sl[a] = sl[a] * exp2f((ml[a] - nm) * LOG2E) + sl2 * exp2f((ml2 - nm) * LOG2E);
      ml[a] = nm;
      float nmt = fmaxf(mt[a], mt2);
      float e1 = exp2f((mt[a] - nmt) * LOG2E);
      float e2 = exp2f((mt2 - nmt) * LOG2E);
      st[a] = st[a] * e1 + st2 * e2;
      dd[a] = dd[a] * e1 + dd2 * e2;
      mt[a] = nmt;
    }
  }

  // cross-wn merge via LDS (reuse As region), one partial per (row, chunk)
  float* M = (float*)smem;   // 128 rows x 5 floats = 2560 B
  if (wn == 1 && q == 0) {
    #pragma unroll
    for (int a = 0; a < 4; ++a) {
      int r = wm * 64 + a * 16 + c15;
      float* p = M + r * 5;
      p[0] = ml[a]; p[1] = sl[a]; p[2] = mt[a]; p[3] = st[a]; p[4] = dd[a];
    }
  }
  __syncthreads();
  if (wn == 0 && q == 0) {
    #pragma unroll
    for (int a = 0; a < 4; ++a) {
      int r = wm * 64 + a * 16 + c15;
      const float* p = M + r * 5;
      float ml2 = p[0], sl2 = p[1], mt2 = p[2], st2 = p[3], dd2 = p[4];
      float nm = fmaxf(ml[a], ml2);
      float slo = sl[a] * exp2f((ml[a] - nm) * LOG2E) + sl2 * exp2f((ml2 - nm) * LOG2E);
      float nmt = fmaxf(mt[a], mt2);
      float e1 = exp2f((mt[a] - nmt) * LOG2E);
      float e2 = exp2f((mt2 - nmt) * LOG2E);
      float sto = st[a] * e1 + st2 * e2;
      float ddo = dd[a] * e1 + dd2 * e2;
      long rg = (long)(brow * BM + r);
      float* o = partials + (rg * NCHUNK + chunk) * 5;
      o[0] = nm; o[1] = slo; o[2] = nmt; o[3] = sto; o[4] = ddo;
    }
  }
}

// ---------------- kernel C: merge partials -> per-row loss ----------------
__global__ void rowloss_kernel(const float* __restrict__ partials,
                               float* __restrict__ rowloss) {
  int r = blockIdx.x * blockDim.x + threadIdx.x;
  if (r >= N_ROWS) return;
  const float* p = partials + (long)r * NCHUNK * 5;
  float ml = -1e30f, sl = 0.f, mt = -1e30f, st = 0.f, dd = 0.f;
  for (int c = 0; c < NCHUNK; ++c) {
    float ml2 = p[0], sl2 = p[1], mt2 = p[2], st2 = p[3], dd2 = p[4];
    p += 5;
    float nm = fmaxf(ml, ml2);
    sl = sl * exp2f((ml - nm) * LOG2E) + sl2 * exp2f((ml2 - nm) * LOG2E);
    ml = nm;
    float nmt = fmaxf(mt, mt2);
    float e1 = exp2f((mt - nmt) * LOG2E);
    float e2 = exp2f((mt2 - nmt) * LOG2E);
    st = st * e1 + st2 * e2;
    dd = dd * e1 + dd2 * e2;
    mt = nmt;
  }
  float lse = ml + logf(sl);
  rowloss[r] = lse - dd / st;
}

// ---------------- kernel D: final scalar reduce ---------------------------
__global__ void final_kernel(const float* __restrict__ rowloss,
                             float* __restrict__ out) {
  __shared__ float sm[4];
  float s = 0.f;
  for (int i = threadIdx.x; i < N_ROWS; i += 256) s += rowloss[i];
  #pragma unroll
  for (int off = 32; off > 0; off >>= 1) s += __shfl_down(s, off);
  if ((threadIdx.x & 63) == 0) sm[threadIdx.x >> 6] = s;
  __syncthreads();
  if (threadIdx.x == 0) out[0] = (sm[0] + sm[1] + sm[2] + sm[3]) * (1.0f / (float)N_ROWS);
}

extern "C" void kernel_launch(void* const* d_in, const int* in_sizes, int n_in,
                              void* d_out, int out_size, void* d_ws, size_t ws_size,
                              hipStream_t stream) {
  const float* x       = (const float*)d_in[0];   // [4096, 512]
  const float* targets = (const float*)d_in[1];   // [4096, 50257]
  const float* weight  = (const float*)d_in[2];   // [50257, 512]
  const float* bias    = (const float*)d_in[3];   // [50257]
  float* out = (float*)d_out;

  char* ws = (char*)d_ws;
  __hip_bfloat16* Wb = (__hip_bfloat16*)ws;                     // 51,511,296 B
  size_t off = (size_t)V_PAD * H_DIM * 2;
  __hip_bfloat16* Xb = (__hip_bfloat16*)(ws + off);             //  4,194,304 B
  off += (size_t)N_ROWS * H_DIM * 2;
  float* partials = (float*)(ws + off);                         // 10,731,520 B
  off += (size_t)N_ROWS * NCHUNK * 5 * sizeof(float);
  float* rowloss = (float*)(ws + off);                          //     16,384 B

  convert_kernel<<<13600, 256, 0, stream>>>(x, weight, Xb, Wb);
  dim3 grid(N_ROWS / BM, NCHUNK);
  fused_kernel<<<grid, 256, 0, stream>>>(Xb, Wb, bias, targets, partials);
  rowloss_kernel<<<N_ROWS / 256, 256, 0, stream>>>(partials, rowloss);
  final_kernel<<<1, 256, 0, stream>>>(rowloss, out);
}

// Round 4
// 869.040 us; speedup vs baseline: 1.8816x; 1.0858x over previous
//
#include <hip/hip_runtime.h>
#include <hip/hip_bf16.h>

#define N_ROWS 4096
#define H_DIM  512
#define V_DIM  50257
#define BM 128
#define BN 128
#define BK 32
#define VT_TOTAL 393            // ceil(V/BN)
#define V_PAD (VT_TOTAL * BN)   // 50304
#define NCHUNK 131              // 393 = 3*131 -> every block exactly 3 tiles
#define LOG2E 1.4426950408889634f

typedef __attribute__((ext_vector_type(8))) short short8;
typedef __attribute__((ext_vector_type(4))) float f32x4;

static __device__ __forceinline__ unsigned short f2bf(float f) {
  unsigned u = __float_as_uint(f);
  u = (u + 0x7fffu + ((u >> 16) & 1u)) >> 16;   // RNE
  return (unsigned short)u;
}

static __device__ __forceinline__ void gload_lds16(const void* g, void* l) {
  __builtin_amdgcn_global_load_lds(
      (const __attribute__((address_space(1))) void*)g,
      (__attribute__((address_space(3))) void*)l, 16, 0, 0);
}

// ---------------- kernel A: fp32 -> bf16 conversion (W padded to V_PAD) ----
__global__ void convert_kernel(const float* __restrict__ X,
                               const float* __restrict__ W,
                               __hip_bfloat16* __restrict__ Xb,
                               __hip_bfloat16* __restrict__ Wb) {
  const long wtot8 = (long)V_PAD * H_DIM / 8;   // 3,219,456
  const long xtot8 = (long)N_ROWS * H_DIM / 8;  //   262,144
  long i = (long)blockIdx.x * blockDim.x + threadIdx.x;
  unsigned short o[8];
  if (i < wtot8) {
    long base = i * 8;
    long row = base >> 9;   // /512
    if (row < V_DIM) {
      const float4* s = (const float4*)(W + base);
      float4 a = s[0], b = s[1];
      o[0]=f2bf(a.x); o[1]=f2bf(a.y); o[2]=f2bf(a.z); o[3]=f2bf(a.w);
      o[4]=f2bf(b.x); o[5]=f2bf(b.y); o[6]=f2bf(b.z); o[7]=f2bf(b.w);
    } else {
      #pragma unroll
      for (int k = 0; k < 8; ++k) o[k] = 0;
    }
    *(short8*)(Wb + base) = *(const short8*)o;
  } else if (i < wtot8 + xtot8) {
    long base = (i - wtot8) * 8;
    const float4* s = (const float4*)(X + base);
    float4 a = s[0], b = s[1];
    o[0]=f2bf(a.x); o[1]=f2bf(a.y); o[2]=f2bf(a.z); o[3]=f2bf(a.w);
    o[4]=f2bf(b.x); o[5]=f2bf(b.y); o[6]=f2bf(b.z); o[7]=f2bf(b.w);
    *(short8*)(Xb + base) = *(const short8*)o;
  }
}

// epilogue: stats update from register-prefetched targets/bias.
// Thread owns 4 x-rows (a, c15) x 16 vocab cols (v0 + b*16 + j).
template <bool GUARD>
static __device__ __forceinline__ void epilogue(
    const f32x4 (&tp)[4][4], const f32x4 (&bp)[4], int v0,
    const f32x4 (&acc)[4][4],
    float ml[4], float sl[4], float mt[4], float st[4], float dd[4]) {
  #pragma unroll
  for (int a = 0; a < 4; ++a) {
    #pragma unroll
    for (int h = 0; h < 2; ++h) {          // halves: b = {2h, 2h+1}
      float T[8], L[8];
      #pragma unroll
      for (int bb = 0; bb < 2; ++bb) {
        const int b = 2 * h + bb;
        #pragma unroll
        for (int j = 0; j < 4; ++j) {
          const int k = bb * 4 + j;
          const bool ok = !GUARD || (v0 + b * 16 + j < V_DIM);
          L[k] = ok ? (acc[a][b][j] + bp[b][j]) : -1e30f;
          T[k] = ok ? tp[a][b][j] : -1e30f;
        }
      }
      // logits lse (online, defer-max thr=12)
      float g = fmaxf(fmaxf(fmaxf(L[0], L[1]), fmaxf(L[2], L[3])),
                      fmaxf(fmaxf(L[4], L[5]), fmaxf(L[6], L[7])));
      if (g > ml[a] + 12.f) {
        sl[a] *= exp2f((ml[a] - g) * LOG2E);
        ml[a] = g;
      }
      float bl = ml[a] * LOG2E;
      float ss = 0.f;
      #pragma unroll
      for (int k = 0; k < 8; ++k)
        ss += exp2f(__builtin_fmaf(L[k], LOG2E, -bl));
      sl[a] += ss;
      // targets softmax num/denom (online, defer-max thr=12)
      float gt = fmaxf(fmaxf(fmaxf(T[0], T[1]), fmaxf(T[2], T[3])),
                       fmaxf(fmaxf(T[4], T[5]), fmaxf(T[6], T[7])));
      if (gt > mt[a] + 12.f) {
        float sc = exp2f((mt[a] - gt) * LOG2E);
        st[a] *= sc; dd[a] *= sc; mt[a] = gt;
      }
      float bt = mt[a] * LOG2E;
      float s2 = 0.f, d2 = 0.f;
      #pragma unroll
      for (int k = 0; k < 8; ++k) {
        float e = exp2f(__builtin_fmaf(T[k], LOG2E, -bt));
        s2 += e;
        d2 = __builtin_fmaf(e, L[k], d2);
      }
      st[a] += s2; dd[a] += d2;
    }
  }
}

// ---------------- kernel B: fused GEMM + online softmax stats -------------
// Grid (32, NCHUNK). Block 256 = 4 waves (2x2 over the 128x128 tile).
// Swapped MFMA: acc[a][b] = mfma(W_frag[b], X_frag[a]) so output cols = x-rows.
// Targets + bias register-prefetched per tile BEFORE the K-loop (MLP).
__global__ __launch_bounds__(256, 2)
void fused_kernel(const __hip_bfloat16* __restrict__ Xb,
                  const __hip_bfloat16* __restrict__ Wb,
                  const float* __restrict__ bias,
                  const float* __restrict__ targets,
                  float* __restrict__ partials) {
  __shared__ __align__(16) char smem[16384];
  __hip_bfloat16* As = (__hip_bfloat16*)smem;          // 8 KB [128][32]
  __hip_bfloat16* Bs = (__hip_bfloat16*)(smem + 8192); // 8 KB [128][32]
  char* AsB = smem;
  char* BsB = smem + 8192;

  const int tid  = threadIdx.x;
  const int lane = tid & 63;
  const int wid  = tid >> 6;
  const int wm   = wid >> 1;
  const int wn   = wid & 1;
  const int q    = lane >> 4;
  const int c15  = lane & 15;
  const int brow = blockIdx.x;
  const int chunk = blockIdx.y;

  float ml[4], sl[4], mt[4], st[4], dd[4];
  #pragma unroll
  for (int a = 0; a < 4; ++a) {
    ml[a] = -1e30f; sl[a] = 0.f; mt[a] = -1e30f; st[a] = 0.f; dd[a] = 0.f;
  }

  const int srow = tid >> 2;
  const int sk   = (tid & 3) * 8;
  const long abase = (long)(brow * BM + srow) * H_DIM + sk;
  // per-thread target row bases (4 rows: a = 0..3)
  const long trow0 = (long)(brow * BM + wm * 64 + c15) * V_DIM;
  const long tlim  = (long)N_ROWS * V_DIM - 4;

  #pragma unroll 1
  for (int vt = chunk; vt < VT_TOTAL; vt += NCHUNK) {
    const int vbase = vt * BN;
    const int v0 = vbase + wn * 64 + q * 4;

    // ---- register prefetch: 16x targets float4 + 4x bias float4 ----
    f32x4 tp[4][4];
    f32x4 bp[4];
    #pragma unroll
    for (int b = 0; b < 4; ++b) {
      int bo = v0 + b * 16;
      bo = bo > (V_DIM - 4) ? (V_DIM - 4) : bo;
      bp[b] = *(const f32x4*)(bias + bo);
    }
    #pragma unroll
    for (int a = 0; a < 4; ++a) {
      const long rb = trow0 + (long)a * 16 * V_DIM + v0;
      #pragma unroll
      for (int b = 0; b < 4; ++b) {
        long off = rb + b * 16;
        off = off > tlim ? tlim : off;
        tp[a][b] = *(const f32x4*)(targets + off);
      }
    }

    f32x4 acc[4][4];
    #pragma unroll
    for (int a = 0; a < 4; ++a)
      #pragma unroll
      for (int b = 0; b < 4; ++b)
        acc[a][b] = (f32x4){0.f, 0.f, 0.f, 0.f};

    const long bbase = (long)(vbase + srow) * H_DIM + sk;

    for (int kk = 0; kk < H_DIM; kk += BK) {
      gload_lds16(Xb + abase + kk,              AsB + wid * 1024);
      gload_lds16(Xb + abase + 64 * H_DIM + kk, AsB + 4096 + wid * 1024);
      gload_lds16(Wb + bbase + kk,              BsB + wid * 1024);
      gload_lds16(Wb + bbase + 64 * H_DIM + kk, BsB + 4096 + wid * 1024);
      __syncthreads();
      short8 xf[4], wf[4];
      #pragma unroll
      for (int a = 0; a < 4; ++a)
        xf[a] = *(const short8*)&As[(wm * 64 + a * 16 + c15) * BK + q * 8];
      #pragma unroll
      for (int b = 0; b < 4; ++b)
        wf[b] = *(const short8*)&Bs[(wn * 64 + b * 16 + c15) * BK + q * 8];
      #pragma unroll
      for (int a = 0; a < 4; ++a)
        #pragma unroll
        for (int b = 0; b < 4; ++b)
          acc[a][b] = __builtin_amdgcn_mfma_f32_16x16x32_bf16(wf[b], xf[a], acc[a][b], 0, 0, 0);
      __syncthreads();
    }

    if (vt == VT_TOTAL - 1)
      epilogue<true>(tp, bp, v0, acc, ml, sl, mt, st, dd);
    else
      epilogue<false>(tp, bp, v0, acc, ml, sl, mt, st, dd);
  }

  // merge the 4 q-lanes (lane bits 4,5) holding disjoint vocab slices
  #pragma unroll
  for (int off = 16; off <= 32; off <<= 1) {
    #pragma unroll
    for (int a = 0; a < 4; ++a) {
      float ml2 = __shfl_xor(ml[a], off);
      float sl2 = __shfl_xor(sl[a], off);
      float mt2 = __shfl_xor(mt[a], off);
      float st2 = __shfl_xor(st[a], off);
      float dd2 = __shfl_xor(dd[a], off);
      float nm = fmaxf(ml[a], ml2);
      sl[a] = sl[a] * exp2f((ml[a] - nm) * LOG2E) + sl2 * exp2f((ml2 - nm) * LOG2E);
      ml[a] = nm;
      float nmt = fmaxf(mt[a], mt2);
      float e1 = exp2f((mt[a] - nmt) * LOG2E);
      float e2 = exp2f((mt2 - nmt) * LOG2E);
      st[a] = st[a] * e1 + st2 * e2;
      dd[a] = dd[a] * e1 + dd2 * e2;
      mt[a] = nmt;
    }
  }

  // cross-wn merge via LDS (reuse As region), one partial per (row, chunk)
  __syncthreads();
  float* M = (float*)smem;   // 128 rows x 5 floats = 2560 B
  if (wn == 1 && q == 0) {
    #pragma unroll
    for (int a = 0; a < 4; ++a) {
      int r = wm * 64 + a * 16 + c15;
      float* p = M + r * 5;
      p[0] = ml[a]; p[1] = sl[a]; p[2] = mt[a]; p[3] = st[a]; p[4] = dd[a];
    }
  }
  __syncthreads();
  if (wn == 0 && q == 0) {
    #pragma unroll
    for (int a = 0; a < 4; ++a) {
      int r = wm * 64 + a * 16 + c15;
      const float* p = M + r * 5;
      float ml2 = p[0], sl2 = p[1], mt2 = p[2], st2 = p[3], dd2 = p[4];
      float nm = fmaxf(ml[a], ml2);
      float slo = sl[a] * exp2f((ml[a] - nm) * LOG2E) + sl2 * exp2f((ml2 - nm) * LOG2E);
      float nmt = fmaxf(mt[a], mt2);
      float e1 = exp2f((mt[a] - nmt) * LOG2E);
      float e2 = exp2f((mt2 - nmt) * LOG2E);
      float sto = st[a] * e1 + st2 * e2;
      float ddo = dd[a] * e1 + dd2 * e2;
      long rg = (long)(brow * BM + r);
      float* o = partials + (rg * NCHUNK + chunk) * 5;
      o[0] = nm; o[1] = slo; o[2] = nmt; o[3] = sto; o[4] = ddo;
    }
  }
}

// ---------------- kernel C: merge partials -> per-row loss ----------------
__global__ void rowloss_kernel(const float* __restrict__ partials,
                               float* __restrict__ rowloss) {
  int r = blockIdx.x * blockDim.x + threadIdx.x;
  if (r >= N_ROWS) return;
  const float* p = partials + (long)r * NCHUNK * 5;
  float ml = -1e30f, sl = 0.f, mt = -1e30f, st = 0.f, dd = 0.f;
  for (int c = 0; c < NCHUNK; ++c) {
    float ml2 = p[0], sl2 = p[1], mt2 = p[2], st2 = p[3], dd2 = p[4];
    p += 5;
    float nm = fmaxf(ml, ml2);
    sl = sl * exp2f((ml - nm) * LOG2E) + sl2 * exp2f((ml2 - nm) * LOG2E);
    ml = nm;
    float nmt = fmaxf(mt, mt2);
    float e1 = exp2f((mt - nmt) * LOG2E);
    float e2 = exp2f((mt2 - nmt) * LOG2E);
    st = st * e1 + st2 * e2;
    dd = dd * e1 + dd2 * e2;
    mt = nmt;
  }
  float lse = ml + logf(sl);
  rowloss[r] = lse - dd / st;
}

// ---------------- kernel D: final scalar reduce ---------------------------
__global__ void final_kernel(const float* __restrict__ rowloss,
                             float* __restrict__ out) {
  __shared__ float sm[4];
  float s = 0.f;
  for (int i = threadIdx.x; i < N_ROWS; i += 256) s += rowloss[i];
  #pragma unroll
  for (int off = 32; off > 0; off >>= 1) s += __shfl_down(s, off);
  if ((threadIdx.x & 63) == 0) sm[threadIdx.x >> 6] = s;
  __syncthreads();
  if (threadIdx.x == 0) out[0] = (sm[0] + sm[1] + sm[2] + sm[3]) * (1.0f / (float)N_ROWS);
}

extern "C" void kernel_launch(void* const* d_in, const int* in_sizes, int n_in,
                              void* d_out, int out_size, void* d_ws, size_t ws_size,
                              hipStream_t stream) {
  const float* x       = (const float*)d_in[0];   // [4096, 512]
  const float* targets = (const float*)d_in[1];   // [4096, 50257]
  const float* weight  = (const float*)d_in[2];   // [50257, 512]
  const float* bias    = (const float*)d_in[3];   // [50257]
  float* out = (float*)d_out;

  char* ws = (char*)d_ws;
  __hip_bfloat16* Wb = (__hip_bfloat16*)ws;                     // 51,511,296 B
  size_t off = (size_t)V_PAD * H_DIM * 2;
  __hip_bfloat16* Xb = (__hip_bfloat16*)(ws + off);             //  4,194,304 B
  off += (size_t)N_ROWS * H_DIM * 2;
  float* partials = (float*)(ws + off);                         // 10,731,520 B
  off += (size_t)N_ROWS * NCHUNK * 5 * sizeof(float);
  float* rowloss = (float*)(ws + off);                          //     16,384 B

  convert_kernel<<<13600, 256, 0, stream>>>(x, weight, Xb, Wb);
  dim3 grid(N_ROWS / BM, NCHUNK);
  fused_kernel<<<grid, 256, 0, stream>>>(Xb, Wb, bias, targets, partials);
  rowloss_kernel<<<N_ROWS / 256, 256, 0, stream>>>(partials, rowloss);
  final_kernel<<<1, 256, 0, stream>>>(rowloss, out);
}